// Round 8
// baseline (198.427 us; speedup 1.0000x reference)
//
#include <hip/hip_runtime.h>

#define NROB 32
#define SEQ 12
#define LOBS 52
#define HID 256
#define LOUT 2
#define KIN 624            // SEQ*LOBS
#define SPB 16             // samples per chunk/block (doubled: halves weight demand)
#define NSD 24             // SEQ*LOUT
#define NBLK 320           // 8 xcds x 40 slots
#define SLOTS 40

// dynamic LDS arena (float offsets):
//   [0,      9984)  x0 [16][624]    (dead after input layer -> x2 [16][256] aliases 0)
//   [10240, 26624)  P  [4][16][256] (dead after L3 finalize -> Wo tile S aliases)
//   [26624, 30720)  x1 [16][256]
#define OFF_P 10240
#define OFF_X1 26624
#define ARENA_F 30720      // 122880 bytes

__device__ __forceinline__ void fma4(float4& a, const float4 w, const float s) {
  a.x = fmaf(w.x, s, a.x);
  a.y = fmaf(w.y, s, a.y);
  a.z = fmaf(w.z, s, a.z);
  a.w = fmaf(w.w, s, a.w);
}

// Stream ROWS weight rows (stride HID floats) against 16 samples (LDS row
// stride XS), acc[m] = float4 of output cols (lane*4). A/B 8-row register
// buffers; 512 FMA (~1024 issue cy) per 8-row group self-covers ~900 cy miss
// latency even at shallow compiler-chosen load depth.
template <int ROWS, int XS>
__device__ __forceinline__ void stream16(const float* __restrict__ wp,
                                         const float* xb, float4* acc) {
  static_assert(ROWS % 16 == 0, "ROWS multiple of 16");
  constexpr int G = ROWS / 8;  // even
  float4 A[8], B[8];
#pragma unroll
  for (int j = 0; j < 8; ++j) A[j] = *(const float4*)(wp + j * HID);
#pragma unroll
  for (int j = 0; j < 8; ++j) B[j] = *(const float4*)(wp + (8 + j) * HID);
#pragma unroll
  for (int g = 0; g < G; g += 2) {
    const int k = g * 8;
#pragma unroll
    for (int m = 0; m < SPB; ++m) {
      const float4 xa = *(const float4*)(xb + m * XS + k);
      const float4 xc = *(const float4*)(xb + m * XS + k + 4);
      fma4(acc[m], A[0], xa.x);
      fma4(acc[m], A[1], xa.y);
      fma4(acc[m], A[2], xa.z);
      fma4(acc[m], A[3], xa.w);
      fma4(acc[m], A[4], xc.x);
      fma4(acc[m], A[5], xc.y);
      fma4(acc[m], A[6], xc.z);
      fma4(acc[m], A[7], xc.w);
    }
    if (g + 2 < G) {
#pragma unroll
      for (int j = 0; j < 8; ++j)
        A[j] = *(const float4*)(wp + (size_t)(k + 16 + j) * HID);
    }
#pragma unroll
    for (int m = 0; m < SPB; ++m) {
      const float4 xa = *(const float4*)(xb + m * XS + k + 8);
      const float4 xc = *(const float4*)(xb + m * XS + k + 12);
      fma4(acc[m], B[0], xa.x);
      fma4(acc[m], B[1], xa.y);
      fma4(acc[m], B[2], xa.z);
      fma4(acc[m], B[3], xa.w);
      fma4(acc[m], B[4], xc.x);
      fma4(acc[m], B[5], xc.y);
      fma4(acc[m], B[6], xc.z);
      fma4(acc[m], B[7], xc.w);
    }
    if (g + 3 < G) {
#pragma unroll
      for (int j = 0; j < 8; ++j)
        B[j] = *(const float4*)(wp + (size_t)(k + 24 + j) * HID);
    }
  }
}

extern __shared__ float arena[];

__global__ __launch_bounds__(512, 2) void k_fused(
    const float* __restrict__ obs, const int* __restrict__ mask,
    const int* __restrict__ ids, const float* __restrict__ Wi,
    const float* __restrict__ bi, const float* __restrict__ W1,
    const float* __restrict__ b1, const float* __restrict__ W2,
    const float* __restrict__ b2, const float* __restrict__ W3,
    const float* __restrict__ b3, const float* __restrict__ Wo,
    const float* __restrict__ bo, float* __restrict__ out) {
  __shared__ int s_cnt[NROB];
  __shared__ int s_wc[8];
  __shared__ int s_h0;
  __shared__ int s_bm[SPB], s_vm[SPB], s_mb[SPB];
  __shared__ float s_ind[SPB][SEQ];
  float* x0 = arena;                 // [16][624]
  float* P = arena + OFF_P;          // [4][16][256]
  float* x1 = arena + OFF_X1;        // [16][256]
  float* x2 = arena;                 // [16][256], aliases dead x0

  const int t = threadIdx.x;
  const int bx = blockIdx.x;

  // ---- phase 0a: histogram ----
  if (t < NROB) s_cnt[t] = 0;
  if (t < SPB) s_bm[t] = 0;
  __syncthreads();
  const int id0 = ids[t];
  const int id1 = ids[t + 512];
  atomicAdd(&s_cnt[id0], 1);
  atomicAdd(&s_cnt[id1], 1);
  __syncthreads();

  // ---- phase 0b: deterministic chunk->block mapping (XCD-swizzled) ----
  int myr = -1, mybase = 0;
  {
    int maxbucket = 0;
    for (int x = 0; x < 8; ++x) {
      int bsum = 0;
      for (int r = x; r < NROB; r += 8) bsum += (s_cnt[r] + SPB - 1) >> 4;
      maxbucket = max(maxbucket, bsum);
    }
    if (maxbucket <= SLOTS) {
      const int myxcd = bx & 7, myslot = bx >> 3;
      int slot = 0;
      for (int r = myxcd; r < NROB; r += 8) {
        const int nch = (s_cnt[r] + SPB - 1) >> 4;
        if (myr < 0 && myslot >= slot && myslot < slot + nch) {
          myr = r;
          mybase = (myslot - slot) * SPB;
        }
        slot += nch;
      }
    } else {
      int ch = 0;
      for (int r = 0; r < NROB; ++r) {
        const int nch = (s_cnt[r] + SPB - 1) >> 4;
        if (myr < 0 && bx >= ch && bx < ch + nch) {
          myr = r;
          mybase = (bx - ch) * SPB;
        }
        ch += nch;
      }
    }
  }
  if (myr < 0) return;  // uniform across block
  const int mycnt = s_cnt[myr];

  // ---- phase 0c: stable sample ranks via ballot scan (two halves) ----
  {
    const int wv = t >> 6;
    const unsigned lane = t & 63;
    const unsigned long long m0 = __ballot(id0 == myr);
    const unsigned long long m1 = __ballot(id1 == myr);
    if (lane == 0) s_wc[wv] = __popcll(m0);
    __syncthreads();
    const unsigned long long below = (1ull << lane) - 1ull;
    int pre0 = 0;
    for (int i = 0; i < wv; ++i) pre0 += s_wc[i];
    if (id0 == myr) {
      const int j = pre0 + __popcll(m0 & below) - mybase;
      if (j >= 0 && j < SPB) s_bm[j] = t;
    }
    __syncthreads();
    if (lane == 0) s_wc[wv] = __popcll(m1);
    if (t == 0) s_h0 = 0;
    __syncthreads();
    int pre1 = 0;
    for (int i = 0; i < wv; ++i) pre1 += s_wc[i];
    if (lane == 0) atomicAdd(&s_h0, __popcll(m0));
    __syncthreads();
    if (id1 == myr) {
      const int j = s_h0 + pre1 + __popcll(m1 & below) - mybase;
      if (j >= 0 && j < SPB) s_bm[j] = t + 512;
    }
    __syncthreads();
  }
  if (t < SPB) {
    const int v = (mybase + t) < mycnt;
    s_vm[t] = v;
    int mb = 0xFFF;  // invalid slot: all-masked -> zero row
    if (v) {
      mb = 0;
      const int b = s_bm[t];
      for (int s = 0; s < SEQ; ++s) mb |= (mask[b * SEQ + s] != 0) << s;
    }
    s_mb[t] = mb;
  }
  __syncthreads();
  if (t < SPB * SEQ) {
    const int m = t / SEQ, s = t - m * SEQ;
    s_ind[m][s] = ((s_mb[m] >> s) & 1) ? 0.f : 1.f;
  }
  // ---- stage masked X0 (156 float4 per sample) ----
  for (int q = t; q < SPB * (KIN / 4); q += 512) {
    const int m = q / 156, f4 = q - m * 156;
    const int s = f4 / 13;
    float4 v = {0.f, 0.f, 0.f, 0.f};
    if (!((s_mb[m] >> s) & 1))
      v = *(const float4*)(obs + (size_t)s_bm[m] * KIN + f4 * 4);
    *(float4*)&x0[m * KIN + f4 * 4] = v;
  }
  __syncthreads();

  const int w = t >> 6, lane = t & 63;
  float* Pp = P + (size_t)(w >> 1) * (SPB * HID) + lane * 4;

  // ---- input layer: waves 0-6 have 80 rows, wave 7 has 64 ----
  {
    float4 acc[SPB];
#pragma unroll
    for (int m = 0; m < SPB; ++m) acc[m] = {0.f, 0.f, 0.f, 0.f};
    const float* Wr = Wi + ((size_t)myr * KIN + w * 80) * HID + lane * 4;
    const float* xb = x0 + w * 80;
    if (w < 7)
      stream16<80, KIN>(Wr, xb, acc);
    else
      stream16<64, KIN>(Wr, xb, acc);
    if ((w & 1) == 0) {
#pragma unroll
      for (int m = 0; m < SPB; ++m) *(float4*)(Pp + m * HID) = acc[m];
    }
    __syncthreads();
    if (w & 1) {
#pragma unroll
      for (int m = 0; m < SPB; ++m) {
        float4 c = *(const float4*)(Pp + m * HID);
        c.x += acc[m].x;
        c.y += acc[m].y;
        c.z += acc[m].z;
        c.w += acc[m].w;
        *(float4*)(Pp + m * HID) = c;
      }
    }
    __syncthreads();
    {  // finalize: 512 thr x 8 cols; sum 4 partials + sum_s ind*bi_s, relu
      const int m = t >> 5, c8 = (t & 31) * 8;
#pragma unroll
      for (int h = 0; h < 8; h += 4) {
        const int c = c8 + h;
        float4 a = {0.f, 0.f, 0.f, 0.f};
#pragma unroll
        for (int j = 0; j < 4; ++j) {
          const float4 p = *(const float4*)&P[(j * SPB + m) * HID + c];
          a.x += p.x;
          a.y += p.y;
          a.z += p.z;
          a.w += p.w;
        }
        const float* br = bi + (size_t)myr * SEQ * HID + c;
#pragma unroll
        for (int s = 0; s < SEQ; ++s)
          fma4(a, *(const float4*)(br + s * HID), s_ind[m][s]);
        float4 o = {fmaxf(a.x, 0.f), fmaxf(a.y, 0.f), fmaxf(a.z, 0.f),
                    fmaxf(a.w, 0.f)};
        *(float4*)&x1[m * HID + c] = o;
      }
    }
    __syncthreads();
  }

  // ---- hidden layers: 32 rows per wave ----
  const float* Ws[3] = {W1, W2, W3};
  const float* bs[3] = {b1, b2, b3};
#pragma unroll
  for (int L = 0; L < 3; ++L) {
    const float* Xin = (L & 1) ? x2 : x1;   // L0: x1->x2, L1: x2->x1, L2: x1->x2
    float* Xout = (L & 1) ? x1 : x2;
    float4 acc[SPB];
#pragma unroll
    for (int m = 0; m < SPB; ++m) acc[m] = {0.f, 0.f, 0.f, 0.f};
    const float* Wr = Ws[L] + ((size_t)myr * HID + w * 32) * HID + lane * 4;
    stream16<32, HID>(Wr, Xin + w * 32, acc);
    if ((w & 1) == 0) {
#pragma unroll
      for (int m = 0; m < SPB; ++m) *(float4*)(Pp + m * HID) = acc[m];
    }
    __syncthreads();
    if (w & 1) {
#pragma unroll
      for (int m = 0; m < SPB; ++m) {
        float4 c = *(const float4*)(Pp + m * HID);
        c.x += acc[m].x;
        c.y += acc[m].y;
        c.z += acc[m].z;
        c.w += acc[m].w;
        *(float4*)(Pp + m * HID) = c;
      }
    }
    __syncthreads();
    {
      const int m = t >> 5, c8 = (t & 31) * 8;
      const float* bb = bs[L] + (size_t)myr * HID;
#pragma unroll
      for (int h = 0; h < 8; h += 4) {
        const int c = c8 + h;
        float4 a = {0.f, 0.f, 0.f, 0.f};
#pragma unroll
        for (int j = 0; j < 4; ++j) {
          const float4 p = *(const float4*)&P[(j * SPB + m) * HID + c];
          a.x += p.x;
          a.y += p.y;
          a.z += p.z;
          a.w += p.w;
        }
        const float4 bv = *(const float4*)(bb + c);
        float4 o = {fmaxf(a.x + bv.x, 0.f), fmaxf(a.y + bv.y, 0.f),
                    fmaxf(a.z + bv.z, 0.f), fmaxf(a.w + bv.w, 0.f)};
        *(float4*)&Xout[m * HID + c] = o;
      }
    }
    __syncthreads();
  }
  // final activations in x2

  // ---- output hypernetwork: Wo tile S[k*25 + sd] (conflict-free), at P ----
  float* S = P;  // 256*25*4 = 25600B, P dead
  {
    const float* Wop = Wo + (size_t)myr * SEQ * HID * LOUT;
    for (int q = t; q < (NSD * HID) / 4; q += 512) {
      const float4 v = *(const float4*)(Wop + q * 4);
      const int flat = q * 4;
      const int s = flat >> 9;          // / (HID*LOUT)
      const int k = (flat & 511) >> 1;  // d-pairs packed in float4
      S[(k + 0) * 25 + s * 2 + 0] = v.x;
      S[(k + 0) * 25 + s * 2 + 1] = v.y;
      S[(k + 1) * 25 + s * 2 + 0] = v.z;
      S[(k + 1) * 25 + s * 2 + 1] = v.w;
    }
  }
  __syncthreads();
  if (t < SPB * NSD) {  // 384 threads: one (sample, s*2+d) each
    const int m = t / NSD, sd = t - m * NSD;
    float a = bo[(size_t)myr * NSD + sd];
    const float* xp = x2 + m * HID;
#pragma unroll 8
    for (int k = 0; k < HID; ++k) a = fmaf(xp[k], S[k * 25 + sd], a);
    if (s_vm[m]) out[(size_t)s_bm[m] * NSD + sd] = a;
  }
}

extern "C" void kernel_launch(void* const* d_in, const int* in_sizes, int n_in,
                              void* d_out, int out_size, void* d_ws, size_t ws_size,
                              hipStream_t stream) {
  const float* obs = (const float*)d_in[0];
  const int* mask = (const int*)d_in[1];
  const int* ids = (const int*)d_in[2];
  const float* Wi = (const float*)d_in[3];
  const float* bi = (const float*)d_in[4];
  const float* W1 = (const float*)d_in[5];
  const float* b1 = (const float*)d_in[6];
  const float* W2 = (const float*)d_in[7];
  const float* b2 = (const float*)d_in[8];
  const float* W3 = (const float*)d_in[9];
  const float* b3 = (const float*)d_in[10];
  const float* Wo = (const float*)d_in[11];
  const float* bo = (const float*)d_in[12];
  float* out = (float*)d_out;
  (void)d_ws;

  // allow 120 KB dynamic LDS (host-side attribute; graph-capture safe)
  (void)hipFuncSetAttribute((const void*)k_fused,
                            hipFuncAttributeMaxDynamicSharedMemorySize,
                            ARENA_F * 4);
  hipLaunchKernelGGL(k_fused, dim3(NBLK), dim3(512), ARENA_F * 4, stream, obs,
                     mask, ids, Wi, bi, W1, b1, W2, b2, W3, b3, Wo, bo, out);
}

// Round 9
// 197.909 us; speedup vs baseline: 1.0026x; 1.0026x over previous
//
#include <hip/hip_runtime.h>

#define NROB 32
#define SEQ 12
#define LOBS 52
#define HID 256
#define LOUT 2
#define KIN 624            // SEQ*LOBS
#define SPB 16             // samples per chunk/block (halves weight demand vs 8)
#define NSD 24             // SEQ*LOUT
#define NBLK 320           // 8 xcds x 40 slots
#define SLOTS 40

// dynamic LDS arena (float offsets):
//   [0,      9984)  x0 [16][624]    (dead after input layer -> x2 [16][256] aliases 0)
//   [10240, 26624)  P  [4][16][256] (dead after L3 finalize -> Wo tile S aliases)
//   [26624, 30720)  x1 [16][256]
#define OFF_P 10240
#define OFF_X1 26624
#define ARENA_F 30720      // 122880 bytes

__device__ __forceinline__ void fma4(float4& a, const float4 w, const float s) {
  a.x = fmaf(w.x, s, a.x);
  a.y = fmaf(w.y, s, a.y);
  a.z = fmaf(w.z, s, a.z);
  a.w = fmaf(w.w, s, a.w);
}

// Stream ROWS weight rows (stride HID floats) against 16 samples (LDS row
// stride XS), acc[m] = float4 of output cols (lane*4). A/B 8-row register
// buffers. Needs ~160-190 VGPR: acc 64 + A/B 64 + addressing -- MUST have the
// 256-VGPR budget (launch_bounds min-waves=1); at 128 it spills (R8: 198us).
template <int ROWS, int XS>
__device__ __forceinline__ void stream16(const float* __restrict__ wp,
                                         const float* xb, float4* acc) {
  static_assert(ROWS % 16 == 0, "ROWS multiple of 16");
  constexpr int G = ROWS / 8;  // even
  float4 A[8], B[8];
#pragma unroll
  for (int j = 0; j < 8; ++j) A[j] = *(const float4*)(wp + j * HID);
#pragma unroll
  for (int j = 0; j < 8; ++j) B[j] = *(const float4*)(wp + (8 + j) * HID);
#pragma unroll
  for (int g = 0; g < G; g += 2) {
    const int k = g * 8;
#pragma unroll
    for (int m = 0; m < SPB; ++m) {
      const float4 xa = *(const float4*)(xb + m * XS + k);
      const float4 xc = *(const float4*)(xb + m * XS + k + 4);
      fma4(acc[m], A[0], xa.x);
      fma4(acc[m], A[1], xa.y);
      fma4(acc[m], A[2], xa.z);
      fma4(acc[m], A[3], xa.w);
      fma4(acc[m], A[4], xc.x);
      fma4(acc[m], A[5], xc.y);
      fma4(acc[m], A[6], xc.z);
      fma4(acc[m], A[7], xc.w);
    }
    if (g + 2 < G) {
#pragma unroll
      for (int j = 0; j < 8; ++j)
        A[j] = *(const float4*)(wp + (size_t)(k + 16 + j) * HID);
    }
#pragma unroll
    for (int m = 0; m < SPB; ++m) {
      const float4 xa = *(const float4*)(xb + m * XS + k + 8);
      const float4 xc = *(const float4*)(xb + m * XS + k + 12);
      fma4(acc[m], B[0], xa.x);
      fma4(acc[m], B[1], xa.y);
      fma4(acc[m], B[2], xa.z);
      fma4(acc[m], B[3], xa.w);
      fma4(acc[m], B[4], xc.x);
      fma4(acc[m], B[5], xc.y);
      fma4(acc[m], B[6], xc.z);
      fma4(acc[m], B[7], xc.w);
    }
    if (g + 3 < G) {
#pragma unroll
      for (int j = 0; j < 8; ++j)
        B[j] = *(const float4*)(wp + (size_t)(k + 24 + j) * HID);
    }
  }
}

extern __shared__ float arena[];

__global__ __launch_bounds__(512, 1) void k_fused(
    const float* __restrict__ obs, const int* __restrict__ mask,
    const int* __restrict__ ids, const float* __restrict__ Wi,
    const float* __restrict__ bi, const float* __restrict__ W1,
    const float* __restrict__ b1, const float* __restrict__ W2,
    const float* __restrict__ b2, const float* __restrict__ W3,
    const float* __restrict__ b3, const float* __restrict__ Wo,
    const float* __restrict__ bo, float* __restrict__ out) {
  __shared__ int s_cnt[NROB];
  __shared__ int s_wc[8];
  __shared__ int s_h0;
  __shared__ int s_bm[SPB], s_vm[SPB], s_mb[SPB];
  __shared__ float s_ind[SPB][SEQ];
  float* x0 = arena;                 // [16][624]
  float* P = arena + OFF_P;          // [4][16][256]
  float* x1 = arena + OFF_X1;        // [16][256]
  float* x2 = arena;                 // [16][256], aliases dead x0

  const int t = threadIdx.x;
  const int bx = blockIdx.x;

  // ---- phase 0a: histogram ----
  if (t < NROB) s_cnt[t] = 0;
  if (t < SPB) s_bm[t] = 0;
  __syncthreads();
  const int id0 = ids[t];
  const int id1 = ids[t + 512];
  atomicAdd(&s_cnt[id0], 1);
  atomicAdd(&s_cnt[id1], 1);
  __syncthreads();

  // ---- phase 0b: deterministic chunk->block mapping (XCD-swizzled) ----
  int myr = -1, mybase = 0;
  {
    int maxbucket = 0;
    for (int x = 0; x < 8; ++x) {
      int bsum = 0;
      for (int r = x; r < NROB; r += 8) bsum += (s_cnt[r] + SPB - 1) >> 4;
      maxbucket = max(maxbucket, bsum);
    }
    if (maxbucket <= SLOTS) {
      const int myxcd = bx & 7, myslot = bx >> 3;
      int slot = 0;
      for (int r = myxcd; r < NROB; r += 8) {
        const int nch = (s_cnt[r] + SPB - 1) >> 4;
        if (myr < 0 && myslot >= slot && myslot < slot + nch) {
          myr = r;
          mybase = (myslot - slot) * SPB;
        }
        slot += nch;
      }
    } else {
      int ch = 0;
      for (int r = 0; r < NROB; ++r) {
        const int nch = (s_cnt[r] + SPB - 1) >> 4;
        if (myr < 0 && bx >= ch && bx < ch + nch) {
          myr = r;
          mybase = (bx - ch) * SPB;
        }
        ch += nch;
      }
    }
  }
  if (myr < 0) return;  // uniform across block
  const int mycnt = s_cnt[myr];

  // ---- phase 0c: stable sample ranks via ballot scan (two halves) ----
  {
    const int wv = t >> 6;
    const unsigned lane = t & 63;
    const unsigned long long m0 = __ballot(id0 == myr);
    const unsigned long long m1 = __ballot(id1 == myr);
    if (lane == 0) s_wc[wv] = __popcll(m0);
    __syncthreads();
    const unsigned long long below = (1ull << lane) - 1ull;
    int pre0 = 0;
    for (int i = 0; i < wv; ++i) pre0 += s_wc[i];
    if (id0 == myr) {
      const int j = pre0 + __popcll(m0 & below) - mybase;
      if (j >= 0 && j < SPB) s_bm[j] = t;
    }
    __syncthreads();
    if (lane == 0) s_wc[wv] = __popcll(m1);
    if (t == 0) s_h0 = 0;
    __syncthreads();
    int pre1 = 0;
    for (int i = 0; i < wv; ++i) pre1 += s_wc[i];
    if (lane == 0) atomicAdd(&s_h0, __popcll(m0));
    __syncthreads();
    if (id1 == myr) {
      const int j = s_h0 + pre1 + __popcll(m1 & below) - mybase;
      if (j >= 0 && j < SPB) s_bm[j] = t + 512;
    }
    __syncthreads();
  }
  if (t < SPB) {
    const int v = (mybase + t) < mycnt;
    s_vm[t] = v;
    int mb = 0xFFF;  // invalid slot: all-masked -> zero row
    if (v) {
      mb = 0;
      const int b = s_bm[t];
      for (int s = 0; s < SEQ; ++s) mb |= (mask[b * SEQ + s] != 0) << s;
    }
    s_mb[t] = mb;
  }
  __syncthreads();
  if (t < SPB * SEQ) {
    const int m = t / SEQ, s = t - m * SEQ;
    s_ind[m][s] = ((s_mb[m] >> s) & 1) ? 0.f : 1.f;
  }
  // ---- stage masked X0 (156 float4 per sample) ----
  for (int q = t; q < SPB * (KIN / 4); q += 512) {
    const int m = q / 156, f4 = q - m * 156;
    const int s = f4 / 13;
    float4 v = {0.f, 0.f, 0.f, 0.f};
    if (!((s_mb[m] >> s) & 1))
      v = *(const float4*)(obs + (size_t)s_bm[m] * KIN + f4 * 4);
    *(float4*)&x0[m * KIN + f4 * 4] = v;
  }
  __syncthreads();

  const int w = t >> 6, lane = t & 63;
  float* Pp = P + (size_t)(w >> 1) * (SPB * HID) + lane * 4;

  // ---- input layer: waves 0-6 have 80 rows, wave 7 has 64 ----
  {
    float4 acc[SPB];
#pragma unroll
    for (int m = 0; m < SPB; ++m) acc[m] = {0.f, 0.f, 0.f, 0.f};
    const float* Wr = Wi + ((size_t)myr * KIN + w * 80) * HID + lane * 4;
    const float* xb = x0 + w * 80;
    if (w < 7)
      stream16<80, KIN>(Wr, xb, acc);
    else
      stream16<64, KIN>(Wr, xb, acc);
    if ((w & 1) == 0) {
#pragma unroll
      for (int m = 0; m < SPB; ++m) *(float4*)(Pp + m * HID) = acc[m];
    }
    __syncthreads();
    if (w & 1) {
#pragma unroll
      for (int m = 0; m < SPB; ++m) {
        float4 c = *(const float4*)(Pp + m * HID);
        c.x += acc[m].x;
        c.y += acc[m].y;
        c.z += acc[m].z;
        c.w += acc[m].w;
        *(float4*)(Pp + m * HID) = c;
      }
    }
    __syncthreads();
    {  // finalize: 512 thr x 8 cols; sum 4 partials + sum_s ind*bi_s, relu
      const int m = t >> 5, c8 = (t & 31) * 8;
#pragma unroll
      for (int h = 0; h < 8; h += 4) {
        const int c = c8 + h;
        float4 a = {0.f, 0.f, 0.f, 0.f};
#pragma unroll
        for (int j = 0; j < 4; ++j) {
          const float4 p = *(const float4*)&P[(j * SPB + m) * HID + c];
          a.x += p.x;
          a.y += p.y;
          a.z += p.z;
          a.w += p.w;
        }
        const float* br = bi + (size_t)myr * SEQ * HID + c;
#pragma unroll
        for (int s = 0; s < SEQ; ++s)
          fma4(a, *(const float4*)(br + s * HID), s_ind[m][s]);
        float4 o = {fmaxf(a.x, 0.f), fmaxf(a.y, 0.f), fmaxf(a.z, 0.f),
                    fmaxf(a.w, 0.f)};
        *(float4*)&x1[m * HID + c] = o;
      }
    }
    __syncthreads();
  }

  // ---- hidden layers: 32 rows per wave ----
  const float* Ws[3] = {W1, W2, W3};
  const float* bs[3] = {b1, b2, b3};
#pragma unroll
  for (int L = 0; L < 3; ++L) {
    const float* Xin = (L & 1) ? x2 : x1;   // L0: x1->x2, L1: x2->x1, L2: x1->x2
    float* Xout = (L & 1) ? x1 : x2;
    float4 acc[SPB];
#pragma unroll
    for (int m = 0; m < SPB; ++m) acc[m] = {0.f, 0.f, 0.f, 0.f};
    const float* Wr = Ws[L] + ((size_t)myr * HID + w * 32) * HID + lane * 4;
    stream16<32, HID>(Wr, Xin + w * 32, acc);
    if ((w & 1) == 0) {
#pragma unroll
      for (int m = 0; m < SPB; ++m) *(float4*)(Pp + m * HID) = acc[m];
    }
    __syncthreads();
    if (w & 1) {
#pragma unroll
      for (int m = 0; m < SPB; ++m) {
        float4 c = *(const float4*)(Pp + m * HID);
        c.x += acc[m].x;
        c.y += acc[m].y;
        c.z += acc[m].z;
        c.w += acc[m].w;
        *(float4*)(Pp + m * HID) = c;
      }
    }
    __syncthreads();
    {
      const int m = t >> 5, c8 = (t & 31) * 8;
      const float* bb = bs[L] + (size_t)myr * HID;
#pragma unroll
      for (int h = 0; h < 8; h += 4) {
        const int c = c8 + h;
        float4 a = {0.f, 0.f, 0.f, 0.f};
#pragma unroll
        for (int j = 0; j < 4; ++j) {
          const float4 p = *(const float4*)&P[(j * SPB + m) * HID + c];
          a.x += p.x;
          a.y += p.y;
          a.z += p.z;
          a.w += p.w;
        }
        const float4 bv = *(const float4*)(bb + c);
        float4 o = {fmaxf(a.x + bv.x, 0.f), fmaxf(a.y + bv.y, 0.f),
                    fmaxf(a.z + bv.z, 0.f), fmaxf(a.w + bv.w, 0.f)};
        *(float4*)&Xout[m * HID + c] = o;
      }
    }
    __syncthreads();
  }
  // final activations in x2

  // ---- output hypernetwork: Wo tile S[k*25 + sd] (conflict-free), at P ----
  float* S = P;  // 256*25*4 = 25600B, P dead
  {
    const float* Wop = Wo + (size_t)myr * SEQ * HID * LOUT;
    for (int q = t; q < (NSD * HID) / 4; q += 512) {
      const float4 v = *(const float4*)(Wop + q * 4);
      const int flat = q * 4;
      const int s = flat >> 9;          // / (HID*LOUT)
      const int k = (flat & 511) >> 1;  // d-pairs packed in float4
      S[(k + 0) * 25 + s * 2 + 0] = v.x;
      S[(k + 0) * 25 + s * 2 + 1] = v.y;
      S[(k + 1) * 25 + s * 2 + 0] = v.z;
      S[(k + 1) * 25 + s * 2 + 1] = v.w;
    }
  }
  __syncthreads();
  if (t < SPB * NSD) {  // 384 threads: one (sample, s*2+d) each
    const int m = t / NSD, sd = t - m * NSD;
    float a = bo[(size_t)myr * NSD + sd];
    const float* xp = x2 + m * HID;
#pragma unroll 8
    for (int k = 0; k < HID; ++k) a = fmaf(xp[k], S[k * 25 + sd], a);
    if (s_vm[m]) out[(size_t)s_bm[m] * NSD + sd] = a;
  }
}

extern "C" void kernel_launch(void* const* d_in, const int* in_sizes, int n_in,
                              void* d_out, int out_size, void* d_ws, size_t ws_size,
                              hipStream_t stream) {
  const float* obs = (const float*)d_in[0];
  const int* mask = (const int*)d_in[1];
  const int* ids = (const int*)d_in[2];
  const float* Wi = (const float*)d_in[3];
  const float* bi = (const float*)d_in[4];
  const float* W1 = (const float*)d_in[5];
  const float* b1 = (const float*)d_in[6];
  const float* W2 = (const float*)d_in[7];
  const float* b2 = (const float*)d_in[8];
  const float* W3 = (const float*)d_in[9];
  const float* b3 = (const float*)d_in[10];
  const float* Wo = (const float*)d_in[11];
  const float* bo = (const float*)d_in[12];
  float* out = (float*)d_out;
  (void)d_ws;

  // allow 120 KB dynamic LDS (host-side attribute; graph-capture safe)
  (void)hipFuncSetAttribute((const void*)k_fused,
                            hipFuncAttributeMaxDynamicSharedMemorySize,
                            ARENA_F * 4);
  hipLaunchKernelGGL(k_fused, dim3(NBLK), dim3(512), ARENA_F * 4, stream, obs,
                     mask, ids, Wi, bi, W1, b1, W2, b2, W3, b3, Wo, bo, out);
}

// Round 10
// 63.740 us; speedup vs baseline: 3.1131x; 3.1049x over previous
//
#include <hip/hip_runtime.h>

#define NROB 32
#define SEQ 12
#define LOBS 52
#define HID 256
#define LOUT 2
#define KIN 624            // SEQ*LOBS
#define SPB 16             // samples per chunk/block
#define NSD 24             // SEQ*LOUT
#define NBLK 320           // 8 xcds x 40 slots
#define SLOTS 40

// dynamic LDS arena (float offsets):
//   [0,      9984)  x0 [16][624]    (dead after input layer -> x2 [16][256] aliases 0)
//   [10240, 26624)  P  [4][16][256] (dead after L3 finalize -> Wo tile S aliases)
//   [26624, 30720)  x1 [16][256]
#define OFF_P 10240
#define OFF_X1 26624
#define ARENA_F 30720      // 122880 bytes

__device__ __forceinline__ void fma2(float2& a, const float2 w, const float s) {
  a.x = fmaf(w.x, s, a.x);
  a.y = fmaf(w.y, s, a.y);
}

// Stream ROWS weight rows against 16 samples. Each lane owns TWO output cols
// (float2): acc[16]=32 VGPR + A/B bufs 32 VGPR => fits the hard 128-VGPR cap
// of a 1024-thread block (R8/R9: full-float4 acc spilled at the 128 cap).
// wp pre-offset to this wave's col-pair base; weights loaded as 512B/wave
// coalesced float2 bursts, 2-group-deep A/B pipeline, x from LDS broadcast.
template <int ROWS, int XS>
__device__ __forceinline__ void stream16(const float* __restrict__ wp,
                                         const float* xb, float2* acc) {
  static_assert(ROWS % 16 == 0, "ROWS multiple of 16");
  constexpr int G = ROWS / 8;  // even
  float2 A[8], B[8];
#pragma unroll
  for (int j = 0; j < 8; ++j) A[j] = *(const float2*)(wp + j * HID);
#pragma unroll
  for (int j = 0; j < 8; ++j) B[j] = *(const float2*)(wp + (8 + j) * HID);
#pragma unroll
  for (int g = 0; g < G; g += 2) {
    const int k = g * 8;
#pragma unroll
    for (int m = 0; m < SPB; ++m) {
      const float4 xa = *(const float4*)(xb + m * XS + k);
      const float4 xc = *(const float4*)(xb + m * XS + k + 4);
      fma2(acc[m], A[0], xa.x);
      fma2(acc[m], A[1], xa.y);
      fma2(acc[m], A[2], xa.z);
      fma2(acc[m], A[3], xa.w);
      fma2(acc[m], A[4], xc.x);
      fma2(acc[m], A[5], xc.y);
      fma2(acc[m], A[6], xc.z);
      fma2(acc[m], A[7], xc.w);
    }
    if (g + 2 < G) {
#pragma unroll
      for (int j = 0; j < 8; ++j)
        A[j] = *(const float2*)(wp + (size_t)(k + 16 + j) * HID);
    }
#pragma unroll
    for (int m = 0; m < SPB; ++m) {
      const float4 xa = *(const float4*)(xb + m * XS + k + 8);
      const float4 xc = *(const float4*)(xb + m * XS + k + 12);
      fma2(acc[m], B[0], xa.x);
      fma2(acc[m], B[1], xa.y);
      fma2(acc[m], B[2], xa.z);
      fma2(acc[m], B[3], xa.w);
      fma2(acc[m], B[4], xc.x);
      fma2(acc[m], B[5], xc.y);
      fma2(acc[m], B[6], xc.z);
      fma2(acc[m], B[7], xc.w);
    }
    if (g + 3 < G) {
#pragma unroll
      for (int j = 0; j < 8; ++j)
        B[j] = *(const float2*)(wp + (size_t)(k + 24 + j) * HID);
    }
  }
}

extern __shared__ float arena[];

__global__ __launch_bounds__(1024, 1) void k_fused(
    const float* __restrict__ obs, const int* __restrict__ mask,
    const int* __restrict__ ids, const float* __restrict__ Wi,
    const float* __restrict__ bi, const float* __restrict__ W1,
    const float* __restrict__ b1, const float* __restrict__ W2,
    const float* __restrict__ b2, const float* __restrict__ W3,
    const float* __restrict__ b3, const float* __restrict__ Wo,
    const float* __restrict__ bo, float* __restrict__ out) {
  __shared__ int s_cnt[NROB];
  __shared__ int s_wc[16];
  __shared__ int s_bm[SPB], s_vm[SPB], s_mb[SPB];
  __shared__ float s_ind[SPB][SEQ];
  float* x0 = arena;                 // [16][624]
  float* P = arena + OFF_P;          // [4][16][256]
  float* x1 = arena + OFF_X1;        // [16][256]
  float* x2 = arena;                 // [16][256], aliases dead x0

  const int t = threadIdx.x;
  const int bx = blockIdx.x;

  // ---- phase 0a: histogram (1024 threads = all samples, one pass) ----
  if (t < NROB) s_cnt[t] = 0;
  if (t < SPB) s_bm[t] = 0;
  __syncthreads();
  const int id0 = ids[t];
  atomicAdd(&s_cnt[id0], 1);
  __syncthreads();

  // ---- phase 0b: deterministic chunk->block mapping (XCD-swizzled) ----
  int myr = -1, mybase = 0;
  {
    int maxbucket = 0;
    for (int x = 0; x < 8; ++x) {
      int bsum = 0;
      for (int r = x; r < NROB; r += 8) bsum += (s_cnt[r] + SPB - 1) >> 4;
      maxbucket = max(maxbucket, bsum);
    }
    if (maxbucket <= SLOTS) {
      const int myxcd = bx & 7, myslot = bx >> 3;
      int slot = 0;
      for (int r = myxcd; r < NROB; r += 8) {
        const int nch = (s_cnt[r] + SPB - 1) >> 4;
        if (myr < 0 && myslot >= slot && myslot < slot + nch) {
          myr = r;
          mybase = (myslot - slot) * SPB;
        }
        slot += nch;
      }
    } else {
      int ch = 0;
      for (int r = 0; r < NROB; ++r) {
        const int nch = (s_cnt[r] + SPB - 1) >> 4;
        if (myr < 0 && bx >= ch && bx < ch + nch) {
          myr = r;
          mybase = (bx - ch) * SPB;
        }
        ch += nch;
      }
    }
  }
  if (myr < 0) return;  // uniform across block
  const int mycnt = s_cnt[myr];

  // ---- phase 0c: stable sample ranks via ballot scan (one pass) ----
  {
    const int wv = t >> 6;
    const unsigned lane = t & 63;
    const unsigned long long m0 = __ballot(id0 == myr);
    if (lane == 0) s_wc[wv] = __popcll(m0);
    __syncthreads();
    int pre = 0;
    for (int i = 0; i < wv; ++i) pre += s_wc[i];
    if (id0 == myr) {
      const unsigned long long below = (1ull << lane) - 1ull;
      const int j = pre + __popcll(m0 & below) - mybase;
      if (j >= 0 && j < SPB) s_bm[j] = t;
    }
    __syncthreads();
  }
  if (t < SPB) {
    const int v = (mybase + t) < mycnt;
    s_vm[t] = v;
    int mb = 0xFFF;  // invalid slot: all-masked -> zero row
    if (v) {
      mb = 0;
      const int b = s_bm[t];
      for (int s = 0; s < SEQ; ++s) mb |= (mask[b * SEQ + s] != 0) << s;
    }
    s_mb[t] = mb;
  }
  __syncthreads();
  if (t < SPB * SEQ) {
    const int m = t / SEQ, s = t - m * SEQ;
    s_ind[m][s] = ((s_mb[m] >> s) & 1) ? 0.f : 1.f;
  }
  // ---- stage masked X0 (156 float4 per sample) ----
  for (int q = t; q < SPB * (KIN / 4); q += 1024) {
    const int m = q / 156, f4 = q - m * 156;
    const int s = f4 / 13;
    float4 v = {0.f, 0.f, 0.f, 0.f};
    if (!((s_mb[m] >> s) & 1))
      v = *(const float4*)(obs + (size_t)s_bm[m] * KIN + f4 * 4);
    *(float4*)&x0[m * KIN + f4 * 4] = v;
  }
  __syncthreads();

  // wave decomposition: 16 waves = 8 K-segs x 2 col-halves; lane owns 2 cols
  const int w = t >> 6, lane = t & 63;
  const int seg = w >> 1, chh = w & 1;
  const int cb = chh * 128 + lane * 2;          // this lane's col pair
  float* Pw = P + (size_t)(seg >> 1) * (SPB * HID) + cb;

  // ---- input layer: segs 0-6 have 80 rows, seg 7 has 64 ----
  {
    float2 acc[SPB];
#pragma unroll
    for (int m = 0; m < SPB; ++m) acc[m] = {0.f, 0.f};
    const float* Wr = Wi + ((size_t)myr * KIN + seg * 80) * HID + cb;
    const float* xb = x0 + seg * 80;
    if (seg < 7)
      stream16<80, KIN>(Wr, xb, acc);
    else
      stream16<64, KIN>(Wr, xb, acc);
    if ((seg & 1) == 0) {
#pragma unroll
      for (int m = 0; m < SPB; ++m) *(float2*)(Pw + m * HID) = acc[m];
    }
    __syncthreads();
    if (seg & 1) {
#pragma unroll
      for (int m = 0; m < SPB; ++m) {
        float2 c = *(const float2*)(Pw + m * HID);
        c.x += acc[m].x;
        c.y += acc[m].y;
        *(float2*)(Pw + m * HID) = c;
      }
    }
    __syncthreads();
    {  // finalize: 1024 thr, one float4 each; + sum_s ind*bi_s, relu -> x1
      const int m = t >> 6, c4 = (t & 63) * 4;
      float4 a = {0.f, 0.f, 0.f, 0.f};
#pragma unroll
      for (int j = 0; j < 4; ++j) {
        const float4 p = *(const float4*)&P[(j * SPB + m) * HID + c4];
        a.x += p.x;
        a.y += p.y;
        a.z += p.z;
        a.w += p.w;
      }
      const float* br = bi + (size_t)myr * SEQ * HID + c4;
#pragma unroll
      for (int s = 0; s < SEQ; ++s) {
        const float4 b4 = *(const float4*)(br + s * HID);
        const float f = s_ind[m][s];
        a.x = fmaf(b4.x, f, a.x);
        a.y = fmaf(b4.y, f, a.y);
        a.z = fmaf(b4.z, f, a.z);
        a.w = fmaf(b4.w, f, a.w);
      }
      float4 o = {fmaxf(a.x, 0.f), fmaxf(a.y, 0.f), fmaxf(a.z, 0.f),
                  fmaxf(a.w, 0.f)};
      *(float4*)&x1[m * HID + c4] = o;
    }
    __syncthreads();
  }

  // ---- hidden layers: 32 rows per seg ----
  const float* Ws[3] = {W1, W2, W3};
  const float* bs[3] = {b1, b2, b3};
#pragma unroll
  for (int L = 0; L < 3; ++L) {
    const float* Xin = (L & 1) ? x2 : x1;  // L0: x1->x2, L1: x2->x1, L2: x1->x2
    float* Xout = (L & 1) ? x1 : x2;
    float2 acc[SPB];
#pragma unroll
    for (int m = 0; m < SPB; ++m) acc[m] = {0.f, 0.f};
    const float* Wr = Ws[L] + ((size_t)myr * HID + seg * 32) * HID + cb;
    stream16<32, HID>(Wr, Xin + seg * 32, acc);
    if ((seg & 1) == 0) {
#pragma unroll
      for (int m = 0; m < SPB; ++m) *(float2*)(Pw + m * HID) = acc[m];
    }
    __syncthreads();
    if (seg & 1) {
#pragma unroll
      for (int m = 0; m < SPB; ++m) {
        float2 c = *(const float2*)(Pw + m * HID);
        c.x += acc[m].x;
        c.y += acc[m].y;
        *(float2*)(Pw + m * HID) = c;
      }
    }
    __syncthreads();
    {
      const int m = t >> 6, c4 = (t & 63) * 4;
      float4 a = {0.f, 0.f, 0.f, 0.f};
#pragma unroll
      for (int j = 0; j < 4; ++j) {
        const float4 p = *(const float4*)&P[(j * SPB + m) * HID + c4];
        a.x += p.x;
        a.y += p.y;
        a.z += p.z;
        a.w += p.w;
      }
      const float4 bv = *(const float4*)(bs[L] + (size_t)myr * HID + c4);
      float4 o = {fmaxf(a.x + bv.x, 0.f), fmaxf(a.y + bv.y, 0.f),
                  fmaxf(a.z + bv.z, 0.f), fmaxf(a.w + bv.w, 0.f)};
      *(float4*)&Xout[m * HID + c4] = o;
    }
    __syncthreads();
  }
  // final activations in x2

  // ---- output hypernetwork: Wo tile S[k*25 + sd] (conflict-free), at P ----
  float* S = P;  // 256*25*4 = 25600B, P dead
  {
    const float* Wop = Wo + (size_t)myr * SEQ * HID * LOUT;
    for (int q = t; q < (NSD * HID) / 4; q += 1024) {
      const float4 v = *(const float4*)(Wop + q * 4);
      const int flat = q * 4;
      const int s = flat >> 9;          // / (HID*LOUT)
      const int k = (flat & 511) >> 1;  // d-pairs packed in float4
      S[(k + 0) * 25 + s * 2 + 0] = v.x;
      S[(k + 0) * 25 + s * 2 + 1] = v.y;
      S[(k + 1) * 25 + s * 2 + 0] = v.z;
      S[(k + 1) * 25 + s * 2 + 1] = v.w;
    }
  }
  __syncthreads();
  if (t < SPB * NSD) {  // 384 threads: one (sample, s*2+d) each
    const int m = t / NSD, sd = t - m * NSD;
    float a = bo[(size_t)myr * NSD + sd];
    const float* xp = x2 + m * HID;
#pragma unroll 8
    for (int k = 0; k < HID; ++k) a = fmaf(xp[k], S[k * 25 + sd], a);
    if (s_vm[m]) out[(size_t)s_bm[m] * NSD + sd] = a;
  }
}

extern "C" void kernel_launch(void* const* d_in, const int* in_sizes, int n_in,
                              void* d_out, int out_size, void* d_ws, size_t ws_size,
                              hipStream_t stream) {
  const float* obs = (const float*)d_in[0];
  const int* mask = (const int*)d_in[1];
  const int* ids = (const int*)d_in[2];
  const float* Wi = (const float*)d_in[3];
  const float* bi = (const float*)d_in[4];
  const float* W1 = (const float*)d_in[5];
  const float* b1 = (const float*)d_in[6];
  const float* W2 = (const float*)d_in[7];
  const float* b2 = (const float*)d_in[8];
  const float* W3 = (const float*)d_in[9];
  const float* b3 = (const float*)d_in[10];
  const float* Wo = (const float*)d_in[11];
  const float* bo = (const float*)d_in[12];
  float* out = (float*)d_out;
  (void)d_ws;

  // allow 120 KB dynamic LDS (host-side attribute; graph-capture safe)
  (void)hipFuncSetAttribute((const void*)k_fused,
                            hipFuncAttributeMaxDynamicSharedMemorySize,
                            ARENA_F * 4);
  hipLaunchKernelGGL(k_fused, dim3(NBLK), dim3(1024), ARENA_F * 4, stream, obs,
                     mask, ids, Wi, bi, W1, b1, W2, b2, W3, b3, Wo, bo, out);
}